// Round 6
// baseline (352.770 us; speedup 1.0000x reference)
//
#include <hip/hip_runtime.h>

#define ALPHA 0.2f
#define NT 1000
#define NRELC 200
#define NE 500000
#define N_ENT 100000
#define CH 4096
#define G 123            // ceil(NE/CH)

// ---------------- int workspace layout (int offsets) ----------------
static constexpr size_t I_STARTS_SRC = 0;        // 1001
static constexpr size_t I_STARTS_DST = 1001;     // 1001
static constexpr size_t I_COLSUM     = 2002;     // 2000 [side][bin]
static constexpr size_t I_HIST2      = 4002;     // 2*G*NT = 246000  [side][blk][bin]
static constexpr size_t I_BASE2      = 250002;   // 246000           [side][blk][bin]
static constexpr size_t I_AB_SRC     = 496002;   // 1000000 (500000 int2: j, oth|rel<<16)
static constexpr size_t I_AB_DST     = 1496002;  // 1000000

// ---------------- float workspace layout (float offsets) ----------------
static constexpr size_t F_S1 = 2496004;              // 500000 x 4 scores (float4/edge)
static constexpr size_t F_U1 = F_S1 + 2000000;       // 4 combos x 3 parts x 64
static constexpr size_t F_U2 = F_U1 + 768;           // 2 combos x 3 parts x 128
static constexpr size_t F_L1 = F_U2 + 768;           // 4 combos x 130000
//   per-combo: P1 @0 (1000x64), P2 @64000 (1000x64), C1 @128000 (1000), C2 @129000 (1000)
static constexpr size_t F_X1 = F_L1 + 4*130000;      // 1000x128
static constexpr size_t F_X2 = F_X1 + 128000;        // 1000x128
static constexpr size_t F_OR = F_X2 + 128000;        // 200x128
static constexpr size_t F_L2 = F_OR + 25600;         // 2 combos x 283800
//   per-combo: Q1 @0 (1000x128), Q2 @128000, R3 @256000 (200x128),
//              C1 @281600 (1000), C2 @282600 (1000), C3 @283600 (200)
static constexpr size_t S2F = 283800;
static constexpr size_t WS_FLOATS = F_L2 + 2*S2F;    // ~5.87M floats = 23.5MB

// ---------------- output layout (floats) ----------------
static constexpr size_t OUT_O2  = 12800000;   // 100000*128
static constexpr size_t OUT_REL = 12928000;   // + 200*128

__device__ __forceinline__ float eluf(float x) { return x > 0.f ? x : expm1f(x); }
__device__ __forceinline__ float scoref(float slin) {
  return expf(slin > 0.f ? -slin : -ALPHA * slin);
}

// ================= sort phase 1: per-chunk histograms =================
__global__ __launch_bounds__(256) void k_hist2(const int* __restrict__ src,
                                               const int* __restrict__ dst,
                                               int* __restrict__ ip) {
  __shared__ int h[NT];
  int bid = blockIdx.x;
  int side = bid >= G;
  int blk = bid - side * G;
  const int* keys = side ? dst : src;
  int j0 = blk * CH;
  int n = min(CH, NE - j0);
  for (int i = threadIdx.x; i < NT; i += 256) h[i] = 0;
  __syncthreads();
  for (int k = threadIdx.x; k < n; k += 256) atomicAdd(&h[keys[j0 + k]], 1);
  __syncthreads();
  int* row = ip + I_HIST2 + (size_t)(side * G + blk) * NT;
  for (int b = threadIdx.x; b < NT; b += 256) row[b] = h[b];
}

// ================= sort phase 2a: column sums (parallel) =================
__global__ void k_colsum(int* __restrict__ ip) {
  int t = blockIdx.x * 256 + threadIdx.x;
  if (t >= 2 * NT) return;
  int side = t / NT, bin = t - side * NT;
  int s = 0;
  for (int blk = 0; blk < G; ++blk)
    s += ip[I_HIST2 + (size_t)(side * G + blk) * NT + bin];
  ip[I_COLSUM + t] = s;
}

// ================= sort phase 2b: prefix over 1000 bins =================
__global__ void k_scan2b(int* __restrict__ ip) {
  __shared__ int buf[1024];
  int t = threadIdx.x;
  for (int side = 0; side < 2; ++side) {
    int v = (t < NT) ? ip[I_COLSUM + side * NT + t] : 0;
    buf[t] = v;
    __syncthreads();
    for (int off = 1; off < 1024; off <<= 1) {
      int x = (t >= off) ? buf[t - off] : 0;
      __syncthreads();
      buf[t] += x;
      __syncthreads();
    }
    int* st = ip + (side ? I_STARTS_DST : I_STARTS_SRC);
    if (t < NT) st[t] = buf[t] - v;
    if (t == NT - 1) st[NT] = buf[t];
    __syncthreads();
  }
}

// ================= sort phase 2c: per-(blk,bin) bases (parallel) ========
__global__ void k_bases(int* __restrict__ ip) {
  int t = blockIdx.x * 256 + threadIdx.x;
  if (t >= 2 * NT) return;
  int side = t / NT, bin = t - side * NT;
  int run = ip[(side ? I_STARTS_DST : I_STARTS_SRC) + bin];
  for (int blk = 0; blk < G; ++blk) {
    size_t idx = I_HIST2 + (size_t)(side * G + blk) * NT + bin;
    int c = ip[idx];
    ip[idx + (I_BASE2 - I_HIST2)] = run;
    run += c;
  }
}

// ================= sort phase 3: LDS-binned scatter =================
__global__ __launch_bounds__(256) void k_binscat(const int* __restrict__ src,
                                                 const int* __restrict__ dst,
                                                 const int* __restrict__ et,
                                                 int* __restrict__ ip) {
  __shared__ int2 bufs[CH];
  __shared__ int loff[1024];
  __shared__ int lcur[1024];
  __shared__ int gbase[1024];
  __shared__ int psum[256];
  int bid = blockIdx.x;
  int side = bid >= G;
  int blk = bid - side * G;
  const int* keys = side ? dst : src;
  const int* oths = side ? src : dst;
  int j0 = blk * CH;
  int n = min(CH, NE - j0);
  int t = threadIdx.x;

  for (int i = t; i < 1024; i += 256) lcur[i] = 0;
  __syncthreads();
  for (int k = t; k < n; k += 256) atomicAdd(&lcur[keys[j0 + k]], 1);
  __syncthreads();
  int c0 = lcur[4*t], c1 = lcur[4*t+1], c2 = lcur[4*t+2], c3 = lcur[4*t+3];
  int s = c0 + c1 + c2 + c3;
  psum[t] = s;
  __syncthreads();
  for (int off = 1; off < 256; off <<= 1) {
    int x = (t >= off) ? psum[t - off] : 0;
    __syncthreads();
    psum[t] += x;
    __syncthreads();
  }
  int base = psum[t] - s;
  loff[4*t]   = base;
  loff[4*t+1] = base + c0;
  loff[4*t+2] = base + c0 + c1;
  loff[4*t+3] = base + c0 + c1 + c2;
  lcur[4*t]   = loff[4*t];
  lcur[4*t+1] = loff[4*t+1];
  lcur[4*t+2] = loff[4*t+2];
  lcur[4*t+3] = loff[4*t+3];
  const int* brow = ip + I_BASE2 + (size_t)(side * G + blk) * NT;
  for (int b = t; b < NT; b += 256) gbase[b] = brow[b];
  __syncthreads();
  for (int k = t; k < n; k += 256) {
    int j = j0 + k;
    int b = keys[j];
    int pos = atomicAdd(&lcur[b], 1);
    bufs[pos] = make_int2(j | (b << 19), oths[j] | (et[j] << 16));
  }
  __syncthreads();
  int2* out = reinterpret_cast<int2*>(ip + (side ? I_AB_DST : I_AB_SRC));
  for (int k = t; k < n; k += 256) {
    int2 q = bufs[k];
    int b = q.x >> 19;
    int posg = gbase[b] + (k - loff[b]);
    out[posg] = make_int2(q.x & 0x7FFFF, q.y);
  }
}

// ================= score-factorization u-vectors =================
__global__ void k_prep_u(const float* aE0, const float* vE0, const float* aT0, const float* vT0,
                         const float* aE1, const float* vE1, const float* aT1, const float* vT1,
                         const float* aEo, const float* vEo, const float* aTo, const float* vTo,
                         float* ws) {
  int t = blockIdx.x * blockDim.x + threadIdx.x;
  if (t < 768) {
    int c = t / 192, rem = t - c*192;
    int p = rem >> 6, k = rem & 63;
    const float* a = (c==0)?aE0:(c==1)?aT0:(c==2)?aE1:aT1;
    const float* v = (c==0)?vE0:(c==1)?vT0:(c==2)?vE1:vT1;
    float s = 0.f;
    for (int o = 0; o < 64; ++o) s += a[o*192 + p*64 + k] * v[o];
    ws[F_U1 + (size_t)(c*3+p)*64 + k] = s;
  } else if (t < 1536) {
    int tt = t - 768;
    int c = tt / 384, rem = tt - c*384;
    int p = rem >> 7, k = rem & 127;
    const float* a = c ? aTo : aEo;
    const float* v = c ? vTo : vEo;
    float s = 0.f;
    for (int o = 0; o < 128; ++o) s += a[o*384 + p*128 + k] * v[o];
    ws[F_U2 + (size_t)(c*3+p)*128 + k] = s;
  }
}

// ================= layer-1 projections P1,P2,C1,C2 =================
__global__ void k_l1_proj(const float* Ent, const float* Typ,
                          const float* aE0, const float* aT0,
                          const float* aE1, const float* aT1,
                          float* ws) {
  int stride = gridDim.x * blockDim.x;
  for (int t = blockIdx.x * blockDim.x + threadIdx.x; t < 4*130000; t += stride) {
    int c = t / 130000, rem = t - c*130000;
    const float* a = (c==0)?aE0:(c==1)?aT0:(c==2)?aE1:aT1;
    float* base = ws + F_L1 + (size_t)c * 130000;
    if (rem < 64000) {
      int i = rem >> 6, o = rem & 63;
      const float* x = Ent + (size_t)i*64;
      const float* ar = a + o*192;
      float s = 0.f;
      #pragma unroll
      for (int k = 0; k < 64; ++k) s += x[k]*ar[k];
      base[rem] = s;
    } else if (rem < 128000) {
      int rr = rem - 64000; int i = rr >> 6, o = rr & 63;
      const float* x = Typ + (size_t)i*64;
      const float* ar = a + o*192 + 64;
      float s = 0.f;
      #pragma unroll
      for (int k = 0; k < 64; ++k) s += x[k]*ar[k];
      base[64000 + rr] = s;
    } else if (rem < 129000) {
      int i = rem - 128000;
      const float* x = Ent + (size_t)i*64;
      const float* u = ws + F_U1 + (size_t)(c*3)*64;
      float s = 0.f;
      #pragma unroll
      for (int k = 0; k < 64; ++k) s += x[k]*u[k];
      base[128000 + i] = s;
    } else {
      int i = rem - 129000;
      const float* x = Typ + (size_t)i*64;
      const float* u = ws + F_U1 + (size_t)(c*3+1)*64;
      float s = 0.f;
      #pragma unroll
      for (int k = 0; k < 64; ++k) s += x[k]*u[k];
      base[129000 + i] = s;
    }
  }
}

// ================= dense layer-1 scores: S4[j] = (s_c0..s_c3) =================
__global__ __launch_bounds__(256) void k_scores1(const float* __restrict__ Eemb,
                                                 const int* __restrict__ src,
                                                 const int* __restrict__ dst,
                                                 float* __restrict__ ws) {
  int t = blockIdx.x * 256 + threadIdx.x;
  int j = t >> 4, sub = t & 15;
  if (j >= NE) return;
  float4 ev = reinterpret_cast<const float4*>(Eemb)[t];
  const float4* U = reinterpret_cast<const float4*>(ws + F_U1);
  float4 w0 = U[ 2*16 + sub];     // combo c: float offset (c*3+2)*64
  float4 w1 = U[ 5*16 + sub];
  float4 w2 = U[ 8*16 + sub];
  float4 w3 = U[11*16 + sub];
  float r0 = ev.x*w0.x + ev.y*w0.y + ev.z*w0.z + ev.w*w0.w;
  float r1 = ev.x*w1.x + ev.y*w1.y + ev.z*w1.z + ev.w*w1.w;
  float r2 = ev.x*w2.x + ev.y*w2.y + ev.z*w2.z + ev.w*w2.w;
  float r3 = ev.x*w3.x + ev.y*w3.y + ev.z*w3.z + ev.w*w3.w;
  #pragma unroll
  for (int s = 1; s < 16; s <<= 1) {
    r0 += __shfl_xor(r0, s, 16);
    r1 += __shfl_xor(r1, s, 16);
    r2 += __shfl_xor(r2, s, 16);
    r3 += __shfl_xor(r3, s, 16);
  }
  if (sub < 4) {
    int si = src[j], di = dst[j];
    float r = sub == 0 ? r0 : sub == 1 ? r1 : sub == 2 ? r2 : r3;
    const float* base = ws + F_L1 + (size_t)sub * 130000;
    ws[F_S1 + (size_t)j*4 + sub] = scoref(base[128000 + si] + base[129000 + di] + r);
  }
}

// ================= layer-1 per-segment accumulate + fused post =================
// grid 2000: blocks [0,1000) = side 0 (seg=src, combos 0,2),
//            blocks [1000,2000) = side 1 (seg=dst, combos 1,3)
__global__ __launch_bounds__(256) void k_l1_acc(const float* __restrict__ Eemb,
                                                const float* aE0, const float* aT0,
                                                const float* aE1, const float* aT1,
                                                const int* __restrict__ ip,
                                                float* __restrict__ ws) {
  __shared__ float Tl[2][NT];
  __shared__ float accR[2][16][64];
  __shared__ float accE[2][64];
  __shared__ float red[256];
  __shared__ float denl[2];

  int side = blockIdx.x >= NT;
  int g = blockIdx.x - side * NT;
  int t = threadIdx.x;
  int sub = t & 15, slot = t >> 4;

  for (int i = t; i < NT; i += 256) { Tl[0][i] = 0.f; Tl[1][i] = 0.f; }
  if (t < 2) denl[t] = 0.f;
  __syncthreads();

  int start = ip[(side ? I_STARTS_DST : I_STARTS_SRC) + g];
  int end   = ip[(side ? I_STARTS_DST : I_STARTS_SRC) + g + 1];
  const int2* ab = reinterpret_cast<const int2*>(ip + (side ? I_AB_DST : I_AB_SRC));
  const float4* S4 = reinterpret_cast<const float4*>(ws + F_S1);

  float4 acc0 = make_float4(0.f,0.f,0.f,0.f);
  float4 acc1 = make_float4(0.f,0.f,0.f,0.f);
  float d0 = 0.f, d1 = 0.f;

  for (int p = start + slot; p < end; p += 16) {
    int2 q = ab[p];
    int j = q.x;
    int oth = q.y & 0xFFFF;
    float4 ev = reinterpret_cast<const float4*>(Eemb)[(size_t)j*16 + sub];
    float4 s4 = S4[j];
    float sA = side ? s4.y : s4.x;
    float sB = side ? s4.w : s4.z;
    acc0.x += sA*ev.x; acc0.y += sA*ev.y; acc0.z += sA*ev.z; acc0.w += sA*ev.w;
    acc1.x += sB*ev.x; acc1.y += sB*ev.y; acc1.z += sB*ev.z; acc1.w += sB*ev.w;
    if (sub == 0) {
      atomicAdd(&Tl[0][oth], sA);
      atomicAdd(&Tl[1][oth], sB);
      d0 += sA; d1 += sB;
    }
  }
  *reinterpret_cast<float4*>(&accR[0][slot][sub*4]) = acc0;
  *reinterpret_cast<float4*>(&accR[1][slot][sub*4]) = acc1;
  if (sub == 0) { atomicAdd(&denl[0], d0); atomicAdd(&denl[1], d1); }
  __syncthreads();
  if (t < 128) {
    int ci = t >> 6, o = t & 63;
    float s = 0.f;
    #pragma unroll
    for (int sl = 0; sl < 16; ++sl) s += accR[ci][sl][o];
    accE[ci][o] = s;
  }
  __syncthreads();

  // fused post: num = den*Pown + Tl@Poth + accE@a3^T ; write x
  int o = t & 63, part = t >> 6;
  size_t othPOff = side ? 0 : 64000;   // P1 : P2
  size_t ownPOff = side ? 64000 : 0;
  #pragma unroll
  for (int ci = 0; ci < 2; ++ci) {
    int c = side + 2*ci;
    const float* Pc = ws + F_L1 + (size_t)c * 130000;
    const float* Poth = Pc + othPOff;
    float sum = 0.f;
    for (int dd = part*250; dd < part*250 + 250; ++dd)
      sum += Tl[ci][dd] * Poth[(size_t)dd*64 + o];
    red[t] = sum;
    __syncthreads();
    if (part == 0) {
      sum = red[o] + red[64+o] + red[128+o] + red[192+o];
      const float* a = (c==0)?aE0:(c==1)?aT0:(c==2)?aE1:aT1;
      const float* a3 = a + o*192 + 128;
      float acc = 0.f;
      #pragma unroll
      for (int k = 0; k < 64; ++k) acc += accE[ci][k]*a3[k];
      float den = denl[ci];
      float own = Pc[ownPOff + (size_t)g*64 + o];
      float num = sum + acc + den*own;
      float h = num / (den == 0.f ? 1.f : den);
      float* dst = ws + (side ? F_X2 : F_X1);
      dst[(size_t)g*128 + ci*64 + o] = eluf(h);
    }
    __syncthreads();
  }
}

// ================= out_rel = Rel @ W =================
__global__ void k_relW(const float* Rel, const float* W, float* ws, float* dout) {
  int t = blockIdx.x * blockDim.x + threadIdx.x;
  if (t >= NRELC*128) return;
  int r = t >> 7, o = t & 127;
  const float* x = Rel + (size_t)r*64;
  float s = 0.f;
  #pragma unroll
  for (int k = 0; k < 64; ++k) s += x[k] * W[(size_t)k*128 + o];
  ws[F_OR + t] = s;
  dout[OUT_REL + t] = s;
}

// ================= layer-2 projections =================
__global__ void k_l2_proj(const float* aEo, const float* aTo, float* ws) {
  int stride = gridDim.x * blockDim.x;
  const float* x1 = ws + F_X1;
  const float* x2 = ws + F_X2;
  const float* orel = ws + F_OR;
  for (int t = blockIdx.x * blockDim.x + threadIdx.x; t < 2*283800; t += stride) {
    int c = t / 283800, rem = t - c*283800;
    const float* a = c ? aTo : aEo;
    float* base = ws + F_L2 + (size_t)c * S2F;
    if (rem < 128000) {
      int i = rem >> 7, o = rem & 127;
      const float* x = x1 + (size_t)i*128;
      const float* ar = a + (size_t)o*384;
      float s = 0.f;
      #pragma unroll
      for (int k = 0; k < 128; ++k) s += x[k]*ar[k];
      base[rem] = s;
    } else if (rem < 256000) {
      int rr = rem - 128000; int i = rr >> 7, o = rr & 127;
      const float* x = x2 + (size_t)i*128;
      const float* ar = a + (size_t)o*384 + 128;
      float s = 0.f;
      #pragma unroll
      for (int k = 0; k < 128; ++k) s += x[k]*ar[k];
      base[128000 + rr] = s;
    } else if (rem < 281600) {
      int rr = rem - 256000; int r = rr >> 7, o = rr & 127;
      const float* x = orel + (size_t)r*128;
      const float* ar = a + (size_t)o*384 + 256;
      float s = 0.f;
      #pragma unroll
      for (int k = 0; k < 128; ++k) s += x[k]*ar[k];
      base[256000 + rr] = s;
    } else if (rem < 282600) {
      int i = rem - 281600;
      const float* u = ws + F_U2 + (size_t)(c*3)*128;
      const float* x = x1 + (size_t)i*128;
      float s = 0.f;
      for (int k = 0; k < 128; ++k) s += x[k]*u[k];
      base[281600 + i] = s;
    } else if (rem < 283600) {
      int i = rem - 282600;
      const float* u = ws + F_U2 + (size_t)(c*3+1)*128;
      const float* x = x2 + (size_t)i*128;
      float s = 0.f;
      for (int k = 0; k < 128; ++k) s += x[k]*u[k];
      base[282600 + i] = s;
    } else {
      int r = rem - 283600;
      const float* u = ws + F_U2 + (size_t)(c*3+2)*128;
      const float* x = orel + (size_t)r*128;
      float s = 0.f;
      for (int k = 0; k < 128; ++k) s += x[k]*u[k];
      base[283600 + r] = s;
    }
  }
}

// ================= layer-2 fused per-segment pass =================
__global__ __launch_bounds__(256) void k_l2_seg(const int* __restrict__ ip,
                                                float* __restrict__ ws,
                                                float* __restrict__ dout) {
  __shared__ float Tl[NT];
  __shared__ float Ul[NRELC];
  __shared__ float cOthL[NT];
  __shared__ float cRelL[NRELC];
  __shared__ float red[256];
  __shared__ float denl;

  int c = blockIdx.x >= NT;
  int g = blockIdx.x - c * NT;
  int t = threadIdx.x;
  float* base = ws + F_L2 + (size_t)c * S2F;

  size_t othOff = c ? 281600 : 282600;   // C1 : C2
  size_t ownOff = c ? 282600 : 281600;
  for (int i = t; i < NT; i += 256) { Tl[i] = 0.f; cOthL[i] = base[othOff + i]; }
  for (int i = t; i < NRELC; i += 256) { Ul[i] = 0.f; cRelL[i] = base[283600 + i]; }
  if (t == 0) denl = 0.f;
  float own = base[ownOff + g];
  __syncthreads();

  int start = ip[(c ? I_STARTS_DST : I_STARTS_SRC) + g];
  int end   = ip[(c ? I_STARTS_DST : I_STARTS_SRC) + g + 1];
  const int2* ab = reinterpret_cast<const int2*>(ip + (c ? I_AB_DST : I_AB_SRC));

  float dpart = 0.f;
  for (int p = start + t; p < end; p += 256) {
    int2 q = ab[p];
    int oth = q.y & 0xFFFF;
    int r = q.y >> 16;
    float sv = scoref(own + cOthL[oth] + cRelL[r]);
    atomicAdd(&Tl[oth], sv);
    atomicAdd(&Ul[r], sv);
    dpart += sv;
  }
  atomicAdd(&denl, dpart);
  __syncthreads();

  int o = t & 127, part = t >> 7;
  const float* Qoth = base + (c ? 0 : 128000);   // Q1 : Q2
  const float* R3 = base + 256000;
  float sum = 0.f;
  for (int dd = part*500; dd < part*500 + 500; ++dd)
    sum += Tl[dd] * Qoth[(size_t)dd*128 + o];
  for (int rr = part*100; rr < part*100 + 100; ++rr)
    sum += Ul[rr] * R3[(size_t)rr*128 + o];
  red[t] = sum;
  __syncthreads();
  if (part == 0) {
    sum = red[o] + red[128+o];
    float den = denl;
    float ownQ = base[(c ? 128000 : 0) + (size_t)g*128 + o];
    float num = sum + den*ownQ;
    float h = num / (den == 0.f ? 1.f : den);
    size_t off = c ? (OUT_O2 + (size_t)g*128 + o) : ((size_t)g*128 + o);
    dout[off] = eluf(h);
  }
}

extern "C" void kernel_launch(void* const* d_in, const int* in_sizes, int n_in,
                              void* d_out, int out_size, void* d_ws, size_t ws_size,
                              hipStream_t stream) {
  (void)in_sizes; (void)n_in;
  const float* Ent = (const float*)d_in[0];
  const float* Typ = (const float*)d_in[1];
  const float* Rel = (const float*)d_in[2];
  const int*   edge = (const int*)d_in[3];
  const int*   etyp = (const int*)d_in[4];
  const float* Eemb = (const float*)d_in[5];
  const float* aE0 = (const float*)d_in[6];
  const float* vE0 = (const float*)d_in[7];
  const float* aT0 = (const float*)d_in[8];
  const float* vT0 = (const float*)d_in[9];
  const float* aE1 = (const float*)d_in[10];
  const float* vE1 = (const float*)d_in[11];
  const float* aT1 = (const float*)d_in[12];
  const float* vT1 = (const float*)d_in[13];
  const float* aEo = (const float*)d_in[14];
  const float* vEo = (const float*)d_in[15];
  const float* aTo = (const float*)d_in[16];
  const float* vTo = (const float*)d_in[17];
  const float* W   = (const float*)d_in[18];
  float* ws  = (float*)d_ws;
  int*   ip  = (int*)d_ws;
  float* out = (float*)d_out;
  const int* srcA = edge;
  const int* dstA = edge + NE;

  if (ws_size < WS_FLOATS * sizeof(float)) return;

  // zero output (o1 rows >= 1000 stay exactly elu(0)=0); all ws arrays are
  // fully overwritten every call -> no ws memset needed (graph-replay safe)
  hipMemsetAsync(d_out, 0, (size_t)out_size * sizeof(float), stream);

  k_hist2  <<<2*G, 256, 0, stream>>>(srcA, dstA, ip);
  k_colsum <<<8, 256, 0, stream>>>(ip);
  k_scan2b <<<1, 1024, 0, stream>>>(ip);
  k_bases  <<<8, 256, 0, stream>>>(ip);
  k_binscat<<<2*G, 256, 0, stream>>>(srcA, dstA, etyp, ip);
  k_prep_u <<<6, 256, 0, stream>>>(aE0,vE0,aT0,vT0,aE1,vE1,aT1,vT1,aEo,vEo,aTo,vTo,ws);
  k_l1_proj<<<2048, 256, 0, stream>>>(Ent, Typ, aE0, aT0, aE1, aT1, ws);
  k_scores1<<<31250, 256, 0, stream>>>(Eemb, srcA, dstA, ws);
  k_l1_acc <<<2000, 256, 0, stream>>>(Eemb, aE0, aT0, aE1, aT1, ip, ws);
  k_relW   <<<100, 256, 0, stream>>>(Rel, W, ws, out);
  k_l2_proj<<<2218, 256, 0, stream>>>(aEo, aTo, ws);
  k_l2_seg <<<2000, 256, 0, stream>>>(ip, ws, out);
}

// Round 8
// 335.471 us; speedup vs baseline: 1.0516x; 1.0516x over previous
//
#include <hip/hip_runtime.h>

#define ALPHA 0.2f
#define NT 1000
#define NRELC 200
#define NE 500000
#define N_ENT 100000
#define CH 4096
#define G 123            // ceil(NE/CH)

// ---------------- int workspace layout (int offsets) ----------------
static constexpr size_t I_STARTS_SRC = 0;        // 1001
static constexpr size_t I_STARTS_DST = 1001;     // 1001
static constexpr size_t I_COLSUM     = 2002;     // 2000 [side][bin]
static constexpr size_t I_HIST2      = 4002;     // 2*G*NT = 246000  [side][blk][bin]
static constexpr size_t I_BASE2      = 250002;   // 246000           [side][blk][bin]
static constexpr size_t I_AB_SRC     = 496002;   // 1000000 (500000 int2: j, oth|rel<<16)
static constexpr size_t I_AB_DST     = 1496002;  // 1000000

// ---------------- float workspace layout (float offsets) ----------------
static constexpr size_t F_SA = 2496004;              // 500000 float2 scores (c0,c2) src side
static constexpr size_t F_SB = F_SA + 1000000;       // 500000 float2 scores (c1,c3) dst side
static constexpr size_t F_U1 = F_SB + 1000000;       // 4 combos x 3 parts x 64
static constexpr size_t F_U2 = F_U1 + 768;           // 2 combos x 3 parts x 128
static constexpr size_t F_L1 = F_U2 + 768;           // 4 combos x 130000
//   per-combo: P1 @0 (1000x64), P2 @64000 (1000x64), C1 @128000 (1000), C2 @129000 (1000)
static constexpr size_t F_X1 = F_L1 + 4*130000;      // 1000x128
static constexpr size_t F_X2 = F_X1 + 128000;        // 1000x128
static constexpr size_t F_OR = F_X2 + 128000;        // 200x128
static constexpr size_t F_L2 = F_OR + 25600;         // 2 combos x 283800
//   per-combo: Q1 @0 (1000x128), Q2 @128000, R3 @256000 (200x128),
//              C1 @281600 (1000), C2 @282600 (1000), C3 @283600 (200)
static constexpr size_t S2F = 283800;
static constexpr size_t WS_FLOATS = F_L2 + 2*S2F;    // ~5.87M floats = 23.5MB

// ---------------- output layout (floats) ----------------
static constexpr size_t OUT_O2  = 12800000;   // 100000*128
static constexpr size_t OUT_REL = 12928000;   // + 200*128

__device__ __forceinline__ float eluf(float x) { return x > 0.f ? x : expm1f(x); }
__device__ __forceinline__ float scoref(float slin) {
  return expf(slin > 0.f ? -slin : -ALPHA * slin);
}

// ================= sort phase 1: per-chunk histograms =================
__global__ __launch_bounds__(256) void k_hist2(const int* __restrict__ src,
                                               const int* __restrict__ dst,
                                               int* __restrict__ ip) {
  __shared__ int h[NT];
  int bid = blockIdx.x;
  int side = bid >= G;
  int blk = bid - side * G;
  const int* keys = side ? dst : src;
  int j0 = blk * CH;
  int n = min(CH, NE - j0);
  for (int i = threadIdx.x; i < NT; i += 256) h[i] = 0;
  __syncthreads();
  for (int k = threadIdx.x; k < n; k += 256) atomicAdd(&h[keys[j0 + k]], 1);
  __syncthreads();
  int* row = ip + I_HIST2 + (size_t)(side * G + blk) * NT;
  for (int b = threadIdx.x; b < NT; b += 256) row[b] = h[b];
}

// ================= sort phase 2a: column sums (parallel) =================
__global__ void k_colsum(int* __restrict__ ip) {
  int t = blockIdx.x * 256 + threadIdx.x;
  if (t >= 2 * NT) return;
  int side = t / NT, bin = t - side * NT;
  int s = 0;
  for (int blk = 0; blk < G; ++blk)
    s += ip[I_HIST2 + (size_t)(side * G + blk) * NT + bin];
  ip[I_COLSUM + t] = s;
}

// ================= sort phase 2b: prefix over 1000 bins =================
__global__ void k_scan2b(int* __restrict__ ip) {
  __shared__ int buf[1024];
  int t = threadIdx.x;
  for (int side = 0; side < 2; ++side) {
    int v = (t < NT) ? ip[I_COLSUM + side * NT + t] : 0;
    buf[t] = v;
    __syncthreads();
    for (int off = 1; off < 1024; off <<= 1) {
      int x = (t >= off) ? buf[t - off] : 0;
      __syncthreads();
      buf[t] += x;
      __syncthreads();
    }
    int* st = ip + (side ? I_STARTS_DST : I_STARTS_SRC);
    if (t < NT) st[t] = buf[t] - v;
    if (t == NT - 1) st[NT] = buf[t];
    __syncthreads();
  }
}

// ================= sort phase 2c: per-(blk,bin) bases (parallel) ========
__global__ void k_bases(int* __restrict__ ip) {
  int t = blockIdx.x * 256 + threadIdx.x;
  if (t >= 2 * NT) return;
  int side = t / NT, bin = t - side * NT;
  int run = ip[(side ? I_STARTS_DST : I_STARTS_SRC) + bin];
  for (int blk = 0; blk < G; ++blk) {
    size_t idx = I_HIST2 + (size_t)(side * G + blk) * NT + bin;
    int c = ip[idx];
    ip[idx + (I_BASE2 - I_HIST2)] = run;
    run += c;
  }
}

// ================= sort phase 3: LDS-binned scatter =================
__global__ __launch_bounds__(256) void k_binscat(const int* __restrict__ src,
                                                 const int* __restrict__ dst,
                                                 const int* __restrict__ et,
                                                 int* __restrict__ ip) {
  __shared__ int2 bufs[CH];
  __shared__ int loff[1024];
  __shared__ int lcur[1024];
  __shared__ int gbase[1024];
  __shared__ int psum[256];
  int bid = blockIdx.x;
  int side = bid >= G;
  int blk = bid - side * G;
  const int* keys = side ? dst : src;
  const int* oths = side ? src : dst;
  int j0 = blk * CH;
  int n = min(CH, NE - j0);
  int t = threadIdx.x;

  for (int i = t; i < 1024; i += 256) lcur[i] = 0;
  __syncthreads();
  for (int k = t; k < n; k += 256) atomicAdd(&lcur[keys[j0 + k]], 1);
  __syncthreads();
  int c0 = lcur[4*t], c1 = lcur[4*t+1], c2 = lcur[4*t+2], c3 = lcur[4*t+3];
  int s = c0 + c1 + c2 + c3;
  psum[t] = s;
  __syncthreads();
  for (int off = 1; off < 256; off <<= 1) {
    int x = (t >= off) ? psum[t - off] : 0;
    __syncthreads();
    psum[t] += x;
    __syncthreads();
  }
  int base = psum[t] - s;
  loff[4*t]   = base;
  loff[4*t+1] = base + c0;
  loff[4*t+2] = base + c0 + c1;
  loff[4*t+3] = base + c0 + c1 + c2;
  lcur[4*t]   = loff[4*t];
  lcur[4*t+1] = loff[4*t+1];
  lcur[4*t+2] = loff[4*t+2];
  lcur[4*t+3] = loff[4*t+3];
  const int* brow = ip + I_BASE2 + (size_t)(side * G + blk) * NT;
  for (int b = t; b < NT; b += 256) gbase[b] = brow[b];
  __syncthreads();
  for (int k = t; k < n; k += 256) {
    int j = j0 + k;
    int b = keys[j];
    int pos = atomicAdd(&lcur[b], 1);
    bufs[pos] = make_int2(j | (b << 19), oths[j] | (et[j] << 16));
  }
  __syncthreads();
  int2* out = reinterpret_cast<int2*>(ip + (side ? I_AB_DST : I_AB_SRC));
  for (int k = t; k < n; k += 256) {
    int2 q = bufs[k];
    int b = q.x >> 19;
    int posg = gbase[b] + (k - loff[b]);
    out[posg] = make_int2(q.x & 0x7FFFF, q.y);
  }
}

// ================= score-factorization u-vectors =================
__global__ void k_prep_u(const float* aE0, const float* vE0, const float* aT0, const float* vT0,
                         const float* aE1, const float* vE1, const float* aT1, const float* vT1,
                         const float* aEo, const float* vEo, const float* aTo, const float* vTo,
                         float* ws) {
  int t = blockIdx.x * blockDim.x + threadIdx.x;
  if (t < 768) {
    int c = t / 192, rem = t - c*192;
    int p = rem >> 6, k = rem & 63;
    const float* a = (c==0)?aE0:(c==1)?aT0:(c==2)?aE1:aT1;
    const float* v = (c==0)?vE0:(c==1)?vT0:(c==2)?vE1:vT1;
    float s = 0.f;
    for (int o = 0; o < 64; ++o) s += a[o*192 + p*64 + k] * v[o];
    ws[F_U1 + (size_t)(c*3+p)*64 + k] = s;
  } else if (t < 1536) {
    int tt = t - 768;
    int c = tt / 384, rem = tt - c*384;
    int p = rem >> 7, k = rem & 127;
    const float* a = c ? aTo : aEo;
    const float* v = c ? vTo : vEo;
    float s = 0.f;
    for (int o = 0; o < 128; ++o) s += a[o*384 + p*128 + k] * v[o];
    ws[F_U2 + (size_t)(c*3+p)*128 + k] = s;
  }
}

// ================= layer-1 projections P1,P2,C1,C2 =================
__global__ void k_l1_proj(const float* Ent, const float* Typ,
                          const float* aE0, const float* aT0,
                          const float* aE1, const float* aT1,
                          float* ws) {
  int stride = gridDim.x * blockDim.x;
  for (int t = blockIdx.x * blockDim.x + threadIdx.x; t < 4*130000; t += stride) {
    int c = t / 130000, rem = t - c*130000;
    const float* a = (c==0)?aE0:(c==1)?aT0:(c==2)?aE1:aT1;
    float* base = ws + F_L1 + (size_t)c * 130000;
    if (rem < 64000) {
      int i = rem >> 6, o = rem & 63;
      const float* x = Ent + (size_t)i*64;
      const float* ar = a + o*192;
      float s = 0.f;
      #pragma unroll
      for (int k = 0; k < 64; ++k) s += x[k]*ar[k];
      base[rem] = s;
    } else if (rem < 128000) {
      int rr = rem - 64000; int i = rr >> 6, o = rr & 63;
      const float* x = Typ + (size_t)i*64;
      const float* ar = a + o*192 + 64;
      float s = 0.f;
      #pragma unroll
      for (int k = 0; k < 64; ++k) s += x[k]*ar[k];
      base[64000 + rr] = s;
    } else if (rem < 129000) {
      int i = rem - 128000;
      const float* x = Ent + (size_t)i*64;
      const float* u = ws + F_U1 + (size_t)(c*3)*64;
      float s = 0.f;
      #pragma unroll
      for (int k = 0; k < 64; ++k) s += x[k]*u[k];
      base[128000 + i] = s;
    } else {
      int i = rem - 129000;
      const float* x = Typ + (size_t)i*64;
      const float* u = ws + F_U1 + (size_t)(c*3+1)*64;
      float s = 0.f;
      #pragma unroll
      for (int k = 0; k < 64; ++k) s += x[k]*u[k];
      base[129000 + i] = s;
    }
  }
}

// ================= dense layer-1 scores, side-partitioned =================
// SA[j] = (s_c0, s_c2)  (src side),  SB[j] = (s_c1, s_c3)  (dst side)
__global__ __launch_bounds__(256) void k_scores1(const float* __restrict__ Eemb,
                                                 const int* __restrict__ src,
                                                 const int* __restrict__ dst,
                                                 float* __restrict__ ws) {
  int t = blockIdx.x * 256 + threadIdx.x;
  int j = t >> 4, sub = t & 15;
  if (j >= NE) return;
  float4 ev = reinterpret_cast<const float4*>(Eemb)[t];
  const float4* U = reinterpret_cast<const float4*>(ws + F_U1);
  float4 w0 = U[ 2*16 + sub];     // combo c: float offset (c*3+2)*64
  float4 w1 = U[ 5*16 + sub];
  float4 w2 = U[ 8*16 + sub];
  float4 w3 = U[11*16 + sub];
  float r0 = ev.x*w0.x + ev.y*w0.y + ev.z*w0.z + ev.w*w0.w;
  float r1 = ev.x*w1.x + ev.y*w1.y + ev.z*w1.z + ev.w*w1.w;
  float r2 = ev.x*w2.x + ev.y*w2.y + ev.z*w2.z + ev.w*w2.w;
  float r3 = ev.x*w3.x + ev.y*w3.y + ev.z*w3.z + ev.w*w3.w;
  #pragma unroll
  for (int s = 1; s < 16; s <<= 1) {
    r0 += __shfl_xor(r0, s, 16);
    r1 += __shfl_xor(r1, s, 16);
    r2 += __shfl_xor(r2, s, 16);
    r3 += __shfl_xor(r3, s, 16);
  }
  if (sub < 4) {
    int si = src[j], di = dst[j];
    float r = sub == 0 ? r0 : sub == 1 ? r1 : sub == 2 ? r2 : r3;
    const float* base = ws + F_L1 + (size_t)sub * 130000;
    float sv = scoref(base[128000 + si] + base[129000 + di] + r);
    // c0 -> SA[2j], c2 -> SA[2j+1], c1 -> SB[2j], c3 -> SB[2j+1]
    size_t off = (sub & 1) ? (F_SB + (size_t)j*2 + (sub >> 1))
                           : (F_SA + (size_t)j*2 + (sub >> 1));
    ws[off] = sv;
  }
}

// ================= layer-1 per-segment accumulate + fused post =================
// grid 2000: blocks [0,1000) = side 0 (seg=src, combos 0,2),
//            blocks [1000,2000) = side 1 (seg=dst, combos 1,3)
__global__ __launch_bounds__(256) void k_l1_acc(const float* __restrict__ Eemb,
                                                const float* aE0, const float* aT0,
                                                const float* aE1, const float* aT1,
                                                const int* __restrict__ ip,
                                                float* __restrict__ ws) {
  __shared__ float Tl[2][NT];
  __shared__ float accR[2][16][64];
  __shared__ float accE[2][64];
  __shared__ float red[256];
  __shared__ float denl[2];

  int side = blockIdx.x >= NT;
  int g = blockIdx.x - side * NT;
  int t = threadIdx.x;
  int sub = t & 15, slot = t >> 4;

  for (int i = t; i < NT; i += 256) { Tl[0][i] = 0.f; Tl[1][i] = 0.f; }
  if (t < 2) denl[t] = 0.f;
  __syncthreads();

  int start = ip[(side ? I_STARTS_DST : I_STARTS_SRC) + g];
  int end   = ip[(side ? I_STARTS_DST : I_STARTS_SRC) + g + 1];
  const int2* ab = reinterpret_cast<const int2*>(ip + (side ? I_AB_DST : I_AB_SRC));
  const float4* EV = reinterpret_cast<const float4*>(Eemb);
  const float2* S2 = reinterpret_cast<const float2*>(ws + (side ? F_SB : F_SA));

  float4 acc0 = make_float4(0.f,0.f,0.f,0.f);
  float4 acc1 = make_float4(0.f,0.f,0.f,0.f);
  float d0 = 0.f, d1 = 0.f;

  int p = start + slot;
  // 4-deep unrolled main loop: 4 q-loads then 8 independent gathers in flight
  for (; p + 48 < end; p += 64) {
    int2 q0 = ab[p], q1 = ab[p+16], q2 = ab[p+32], q3 = ab[p+48];
    float4 e0 = EV[(size_t)q0.x*16 + sub];
    float4 e1 = EV[(size_t)q1.x*16 + sub];
    float4 e2 = EV[(size_t)q2.x*16 + sub];
    float4 e3 = EV[(size_t)q3.x*16 + sub];
    float2 s0 = S2[q0.x], s1 = S2[q1.x], s2 = S2[q2.x], s3 = S2[q3.x];
    acc0.x += s0.x*e0.x + s1.x*e1.x + s2.x*e2.x + s3.x*e3.x;
    acc0.y += s0.x*e0.y + s1.x*e1.y + s2.x*e2.y + s3.x*e3.y;
    acc0.z += s0.x*e0.z + s1.x*e1.z + s2.x*e2.z + s3.x*e3.z;
    acc0.w += s0.x*e0.w + s1.x*e1.w + s2.x*e2.w + s3.x*e3.w;
    acc1.x += s0.y*e0.x + s1.y*e1.x + s2.y*e2.x + s3.y*e3.x;
    acc1.y += s0.y*e0.y + s1.y*e1.y + s2.y*e2.y + s3.y*e3.y;
    acc1.z += s0.y*e0.z + s1.y*e1.z + s2.y*e2.z + s3.y*e3.z;
    acc1.w += s0.y*e0.w + s1.y*e1.w + s2.y*e2.w + s3.y*e3.w;
    if (sub == 0) {
      atomicAdd(&Tl[0][q0.y & 0xFFFF], s0.x); atomicAdd(&Tl[1][q0.y & 0xFFFF], s0.y);
      atomicAdd(&Tl[0][q1.y & 0xFFFF], s1.x); atomicAdd(&Tl[1][q1.y & 0xFFFF], s1.y);
      atomicAdd(&Tl[0][q2.y & 0xFFFF], s2.x); atomicAdd(&Tl[1][q2.y & 0xFFFF], s2.y);
      atomicAdd(&Tl[0][q3.y & 0xFFFF], s3.x); atomicAdd(&Tl[1][q3.y & 0xFFFF], s3.y);
      d0 += s0.x + s1.x + s2.x + s3.x;
      d1 += s0.y + s1.y + s2.y + s3.y;
    }
  }
  for (; p < end; p += 16) {
    int2 q = ab[p];
    float4 ev = EV[(size_t)q.x*16 + sub];
    float2 s = S2[q.x];
    acc0.x += s.x*ev.x; acc0.y += s.x*ev.y; acc0.z += s.x*ev.z; acc0.w += s.x*ev.w;
    acc1.x += s.y*ev.x; acc1.y += s.y*ev.y; acc1.z += s.y*ev.z; acc1.w += s.y*ev.w;
    if (sub == 0) {
      atomicAdd(&Tl[0][q.y & 0xFFFF], s.x);
      atomicAdd(&Tl[1][q.y & 0xFFFF], s.y);
      d0 += s.x; d1 += s.y;
    }
  }
  *reinterpret_cast<float4*>(&accR[0][slot][sub*4]) = acc0;
  *reinterpret_cast<float4*>(&accR[1][slot][sub*4]) = acc1;
  if (sub == 0) { atomicAdd(&denl[0], d0); atomicAdd(&denl[1], d1); }
  __syncthreads();
  if (t < 128) {
    int ci = t >> 6, o = t & 63;
    float s = 0.f;
    #pragma unroll
    for (int sl = 0; sl < 16; ++sl) s += accR[ci][sl][o];
    accE[ci][o] = s;
  }
  __syncthreads();

  // fused post: num = den*Pown + Tl@Poth + accE@a3^T ; write x
  int o = t & 63, part = t >> 6;
  size_t othPOff = side ? 0 : 64000;   // P1 : P2
  size_t ownPOff = side ? 64000 : 0;
  #pragma unroll
  for (int ci = 0; ci < 2; ++ci) {
    int c = side + 2*ci;
    const float* Pc = ws + F_L1 + (size_t)c * 130000;
    const float* Poth = Pc + othPOff;
    float sum = 0.f;
    for (int dd = part*250; dd < part*250 + 250; ++dd)
      sum += Tl[ci][dd] * Poth[(size_t)dd*64 + o];
    red[t] = sum;
    __syncthreads();
    if (part == 0) {
      sum = red[o] + red[64+o] + red[128+o] + red[192+o];
      const float* a = (c==0)?aE0:(c==1)?aT0:(c==2)?aE1:aT1;
      const float* a3 = a + o*192 + 128;
      float acc = 0.f;
      #pragma unroll
      for (int k = 0; k < 64; ++k) acc += accE[ci][k]*a3[k];
      float den = denl[ci];
      float own = Pc[ownPOff + (size_t)g*64 + o];
      float num = sum + acc + den*own;
      float h = num / (den == 0.f ? 1.f : den);
      float* dst = ws + (side ? F_X2 : F_X1);
      dst[(size_t)g*128 + ci*64 + o] = eluf(h);
    }
    __syncthreads();
  }
}

// ================= out_rel = Rel @ W =================
__global__ void k_relW(const float* Rel, const float* W, float* ws, float* dout) {
  int t = blockIdx.x * blockDim.x + threadIdx.x;
  if (t >= NRELC*128) return;
  int r = t >> 7, o = t & 127;
  const float* x = Rel + (size_t)r*64;
  float s = 0.f;
  #pragma unroll
  for (int k = 0; k < 64; ++k) s += x[k] * W[(size_t)k*128 + o];
  ws[F_OR + t] = s;
  dout[OUT_REL + t] = s;
}

// ================= layer-2 projections =================
__global__ void k_l2_proj(const float* aEo, const float* aTo, float* ws) {
  int stride = gridDim.x * blockDim.x;
  const float* x1 = ws + F_X1;
  const float* x2 = ws + F_X2;
  const float* orel = ws + F_OR;
  for (int t = blockIdx.x * blockDim.x + threadIdx.x; t < 2*283800; t += stride) {
    int c = t / 283800, rem = t - c*283800;
    const float* a = c ? aTo : aEo;
    float* base = ws + F_L2 + (size_t)c * S2F;
    if (rem < 128000) {
      int i = rem >> 7, o = rem & 127;
      const float* x = x1 + (size_t)i*128;
      const float* ar = a + (size_t)o*384;
      float s = 0.f;
      #pragma unroll
      for (int k = 0; k < 128; ++k) s += x[k]*ar[k];
      base[rem] = s;
    } else if (rem < 256000) {
      int rr = rem - 128000; int i = rr >> 7, o = rr & 127;
      const float* x = x2 + (size_t)i*128;
      const float* ar = a + (size_t)o*384 + 128;
      float s = 0.f;
      #pragma unroll
      for (int k = 0; k < 128; ++k) s += x[k]*ar[k];
      base[128000 + rr] = s;
    } else if (rem < 281600) {
      int rr = rem - 256000; int r = rr >> 7, o = rr & 127;
      const float* x = orel + (size_t)r*128;
      const float* ar = a + (size_t)o*384 + 256;
      float s = 0.f;
      #pragma unroll
      for (int k = 0; k < 128; ++k) s += x[k]*ar[k];
      base[256000 + rr] = s;
    } else if (rem < 282600) {
      int i = rem - 281600;
      const float* u = ws + F_U2 + (size_t)(c*3)*128;
      const float* x = x1 + (size_t)i*128;
      float s = 0.f;
      for (int k = 0; k < 128; ++k) s += x[k]*u[k];
      base[281600 + i] = s;
    } else if (rem < 283600) {
      int i = rem - 282600;
      const float* u = ws + F_U2 + (size_t)(c*3+1)*128;
      const float* x = x2 + (size_t)i*128;
      float s = 0.f;
      for (int k = 0; k < 128; ++k) s += x[k]*u[k];
      base[282600 + i] = s;
    } else {
      int r = rem - 283600;
      const float* u = ws + F_U2 + (size_t)(c*3+2)*128;
      const float* x = orel + (size_t)r*128;
      float s = 0.f;
      for (int k = 0; k < 128; ++k) s += x[k]*u[k];
      base[283600 + r] = s;
    }
  }
}

// ================= layer-2 fused per-segment pass =================
__global__ __launch_bounds__(256) void k_l2_seg(const int* __restrict__ ip,
                                                float* __restrict__ ws,
                                                float* __restrict__ dout) {
  __shared__ float Tl[NT];
  __shared__ float Ul[NRELC];
  __shared__ float cOthL[NT];
  __shared__ float cRelL[NRELC];
  __shared__ float red[256];
  __shared__ float denl;

  int c = blockIdx.x >= NT;
  int g = blockIdx.x - c * NT;
  int t = threadIdx.x;
  float* base = ws + F_L2 + (size_t)c * S2F;

  size_t othOff = c ? 281600 : 282600;   // C1 : C2
  size_t ownOff = c ? 282600 : 281600;
  for (int i = t; i < NT; i += 256) { Tl[i] = 0.f; cOthL[i] = base[othOff + i]; }
  for (int i = t; i < NRELC; i += 256) { Ul[i] = 0.f; cRelL[i] = base[283600 + i]; }
  if (t == 0) denl = 0.f;
  float own = base[ownOff + g];
  __syncthreads();

  int start = ip[(c ? I_STARTS_DST : I_STARTS_SRC) + g];
  int end   = ip[(c ? I_STARTS_DST : I_STARTS_SRC) + g + 1];
  const int2* ab = reinterpret_cast<const int2*>(ip + (c ? I_AB_DST : I_AB_SRC));

  float dpart = 0.f;
  for (int p = start + t; p < end; p += 256) {
    int2 q = ab[p];
    int oth = q.y & 0xFFFF;
    int r = q.y >> 16;
    float sv = scoref(own + cOthL[oth] + cRelL[r]);
    atomicAdd(&Tl[oth], sv);
    atomicAdd(&Ul[r], sv);
    dpart += sv;
  }
  atomicAdd(&denl, dpart);
  __syncthreads();

  int o = t & 127, part = t >> 7;
  const float* Qoth = base + (c ? 0 : 128000);   // Q1 : Q2
  const float* R3 = base + 256000;
  float sum = 0.f;
  for (int dd = part*500; dd < part*500 + 500; ++dd)
    sum += Tl[dd] * Qoth[(size_t)dd*128 + o];
  for (int rr = part*100; rr < part*100 + 100; ++rr)
    sum += Ul[rr] * R3[(size_t)rr*128 + o];
  red[t] = sum;
  __syncthreads();
  if (part == 0) {
    sum = red[o] + red[128+o];
    float den = denl;
    float ownQ = base[(c ? 128000 : 0) + (size_t)g*128 + o];
    float num = sum + den*ownQ;
    float h = num / (den == 0.f ? 1.f : den);
    size_t off = c ? (OUT_O2 + (size_t)g*128 + o) : ((size_t)g*128 + o);
    dout[off] = eluf(h);
  }
}

extern "C" void kernel_launch(void* const* d_in, const int* in_sizes, int n_in,
                              void* d_out, int out_size, void* d_ws, size_t ws_size,
                              hipStream_t stream) {
  (void)in_sizes; (void)n_in;
  const float* Ent = (const float*)d_in[0];
  const float* Typ = (const float*)d_in[1];
  const float* Rel = (const float*)d_in[2];
  const int*   edge = (const int*)d_in[3];
  const int*   etyp = (const int*)d_in[4];
  const float* Eemb = (const float*)d_in[5];
  const float* aE0 = (const float*)d_in[6];
  const float* vE0 = (const float*)d_in[7];
  const float* aT0 = (const float*)d_in[8];
  const float* vT0 = (const float*)d_in[9];
  const float* aE1 = (const float*)d_in[10];
  const float* vE1 = (const float*)d_in[11];
  const float* aT1 = (const float*)d_in[12];
  const float* vT1 = (const float*)d_in[13];
  const float* aEo = (const float*)d_in[14];
  const float* vEo = (const float*)d_in[15];
  const float* aTo = (const float*)d_in[16];
  const float* vTo = (const float*)d_in[17];
  const float* W   = (const float*)d_in[18];
  float* ws  = (float*)d_ws;
  int*   ip  = (int*)d_ws;
  float* out = (float*)d_out;
  const int* srcA = edge;
  const int* dstA = edge + NE;

  if (ws_size < WS_FLOATS * sizeof(float)) return;

  // zero output (o1 rows >= 1000 stay exactly elu(0)=0); all ws arrays are
  // fully overwritten every call -> no ws memset needed (graph-replay safe)
  hipMemsetAsync(d_out, 0, (size_t)out_size * sizeof(float), stream);

  k_hist2  <<<2*G, 256, 0, stream>>>(srcA, dstA, ip);
  k_colsum <<<8, 256, 0, stream>>>(ip);
  k_scan2b <<<1, 1024, 0, stream>>>(ip);
  k_bases  <<<8, 256, 0, stream>>>(ip);
  k_binscat<<<2*G, 256, 0, stream>>>(srcA, dstA, etyp, ip);
  k_prep_u <<<6, 256, 0, stream>>>(aE0,vE0,aT0,vT0,aE1,vE1,aT1,vT1,aEo,vEo,aTo,vTo,ws);
  k_l1_proj<<<2048, 256, 0, stream>>>(Ent, Typ, aE0, aT0, aE1, aT1, ws);
  k_scores1<<<31250, 256, 0, stream>>>(Eemb, srcA, dstA, ws);
  k_l1_acc <<<2000, 256, 0, stream>>>(Eemb, aE0, aT0, aE1, aT1, ip, ws);
  k_relW   <<<100, 256, 0, stream>>>(Rel, W, ws, out);
  k_l2_proj<<<2218, 256, 0, stream>>>(aEo, aTo, ws);
  k_l2_seg <<<2000, 256, 0, stream>>>(ip, ws, out);
}